// Round 2
// baseline (1588.268 us; speedup 1.0000x reference)
//
#include <hip/hip_runtime.h>
#include <hip/hip_bf16.h>
#include <math.h>

#define N_SEQ  2048
#define DMODEL 2048
#define NHEAD  16
#define HDIM   128
#define QKV_LD 6144   // 3*DMODEL

// ---------------------------------------------------------------------------
// fp32 GEMM: C[M,N] = A[M,K] @ B[K,N].  128x128 tile, BK=16, 256 threads,
// 8x8 microtile split into 4 quadrants (conflict-free float4 LDS reads).
// ---------------------------------------------------------------------------
#define BM 128
#define BN 128
#define BKG 16

__global__ __launch_bounds__(256, 2)
void gemm_f32(const float* __restrict__ A, const float* __restrict__ B,
              float* __restrict__ C, int M, int N, int K,
              int lda, int ldb, int ldc)
{
    __shared__ float As[BKG][132];   // transposed: As[k][m]
    __shared__ float Bs[BKG][132];   // Bs[k][n]

    const int t  = threadIdx.x;
    const int tx = t & 15;           // n-group
    const int ty = t >> 4;           // m-group
    const int bm = blockIdx.y * BM;
    const int bn = blockIdx.x * BN;

    // staging assignments
    const int am  = t >> 2;          // A row (and +64)
    const int ak  = (t & 3) << 2;    // A k-offset (float4)
    const int bk  = t >> 5;          // B k row (and +8)
    const int bn4 = (t & 31) << 2;   // B col (float4)

    float acc[8][8];
    #pragma unroll
    for (int i = 0; i < 8; ++i)
        #pragma unroll
        for (int j = 0; j < 8; ++j) acc[i][j] = 0.f;

    for (int k0 = 0; k0 < K; k0 += BKG) {
        // issue global loads BEFORE the barrier (overlap with prior compute)
        const float4 a0 = *(const float4*)&A[(size_t)(bm + am)      * lda + k0 + ak];
        const float4 a1 = *(const float4*)&A[(size_t)(bm + am + 64) * lda + k0 + ak];
        const float4 b0 = *(const float4*)&B[(size_t)(k0 + bk)     * ldb + bn + bn4];
        const float4 b1 = *(const float4*)&B[(size_t)(k0 + bk + 8) * ldb + bn + bn4];
        __syncthreads();
        As[ak+0][am]    = a0.x; As[ak+1][am]    = a0.y; As[ak+2][am]    = a0.z; As[ak+3][am]    = a0.w;
        As[ak+0][am+64] = a1.x; As[ak+1][am+64] = a1.y; As[ak+2][am+64] = a1.z; As[ak+3][am+64] = a1.w;
        *(float4*)&Bs[bk][bn4]   = b0;
        *(float4*)&Bs[bk+8][bn4] = b1;
        __syncthreads();

        #pragma unroll
        for (int kk = 0; kk < BKG; ++kk) {
            const float4 A0 = *(const float4*)&As[kk][ty << 2];
            const float4 A1 = *(const float4*)&As[kk][(ty << 2) + 64];
            const float4 B0 = *(const float4*)&Bs[kk][tx << 2];
            const float4 B1 = *(const float4*)&Bs[kk][(tx << 2) + 64];
            const float a[8] = {A0.x, A0.y, A0.z, A0.w, A1.x, A1.y, A1.z, A1.w};
            const float b[8] = {B0.x, B0.y, B0.z, B0.w, B1.x, B1.y, B1.z, B1.w};
            #pragma unroll
            for (int i = 0; i < 8; ++i)
                #pragma unroll
                for (int j = 0; j < 8; ++j)
                    acc[i][j] = fmaf(a[i], b[j], acc[i][j]);
        }
    }

    #pragma unroll
    for (int i = 0; i < 8; ++i) {
        const int m = bm + ((i < 4) ? ((ty << 2) + i) : (64 + (ty << 2) + i - 4));
        const float4 o0 = make_float4(acc[i][0], acc[i][1], acc[i][2], acc[i][3]);
        const float4 o1 = make_float4(acc[i][4], acc[i][5], acc[i][6], acc[i][7]);
        *(float4*)&C[(size_t)m * ldc + bn + (tx << 2)]      = o0;
        *(float4*)&C[(size_t)m * ldc + bn + 64 + (tx << 2)] = o1;
    }
}

// ---------------------------------------------------------------------------
// Flash-style causal attention, fp32.
// grid = (N/64, H), 256 threads. One 64-row Q tile per block.
// qkv layout: row n, cols [0,2048)=Q, [2048,4096)=K, [4096,6144)=V,
// head h occupies 128 contiguous cols within each third.
// ---------------------------------------------------------------------------
#define QB 64
#define KB 64
#define PQT 68    // pitch for Qt/Kt/St (pad, float4-aligned)

__device__ __forceinline__ int swz(int c, int k) { return c ^ ((k >> 3) & 7); }

__global__ __launch_bounds__(256, 1)
void attn_f32(const float* __restrict__ qkv, float* __restrict__ out)
{
    __shared__ float Qt[HDIM][PQT];   // [k][m], swizzled float4 column groups
    __shared__ float Kt[HDIM][PQT];   // [k][j], swizzled
    __shared__ float Vs[KB][132];     // [j][kk] natural
    __shared__ float St[KB][PQT];     // [j][m]
    __shared__ float pmax[4][QB];     // per-segment row max partials
    __shared__ float psum[4][QB];     // per-segment row sum partials
    __shared__ float rowm[QB];        // broadcast: new running max
    __shared__ float rowstat[QB];     // broadcast: corr, then 1/l

    const int t    = threadIdx.x;
    const int h    = blockIdx.y;
    const int qb   = blockIdx.x;
    const int row0 = qb * QB;

    const int lc = t & 31;   // float4 column for staging (k/4)
    const int lr = t >> 5;   // row group 0..7

    // ---- stage Q (transposed + swizzled), once
    {
        const float* qbase = qkv + (size_t)row0 * QKV_LD + h * HDIM;
        #pragma unroll
        for (int r = 0; r < 8; ++r) {
            const int m  = lr + r * 8;
            const float4 q = *(const float4*)&qbase[(size_t)m * QKV_LD + (lc << 2)];
            const int kb4 = lc << 2;
            Qt[kb4+0][(swz(m >> 2, kb4+0) << 2) + (m & 3)] = q.x;
            Qt[kb4+1][(swz(m >> 2, kb4+1) << 2) + (m & 3)] = q.y;
            Qt[kb4+2][(swz(m >> 2, kb4+2) << 2) + (m & 3)] = q.z;
            Qt[kb4+3][(swz(m >> 2, kb4+3) << 2) + (m & 3)] = q.w;
        }
    }

    float m_run = -3.0e38f, l_run = 0.f;   // live in threads t<QB only
    float o[4][8];
    #pragma unroll
    for (int i = 0; i < 4; ++i)
        #pragma unroll
        for (int j = 0; j < 8; ++j) o[i][j] = 0.f;

    const int cq = t & 15;          // S microtile m-group (cols of St)
    const int cj = t >> 4;          // S microtile j-group (rows of St) 0..15
    const int om = (t >> 4) << 2;   // O rows base (4 rows)
    const int oc = (t & 15) << 2;   // O col base (and +64)
    const int srow = t & 63;        // softmax: row this thread helps with
    const int sseg = t >> 6;        // softmax: which 16-j segment

    const float scale = 0.08838834764831845f;  // 1/sqrt(128)
    const int ntiles = qb + 1;

    for (int jt = 0; jt < ntiles; ++jt) {
        const int jbase = jt * KB;

        // prefetch K/V tile to registers before the barrier
        float4 kreg[8], vreg[8];
        {
            const float* kbaseg = qkv + (size_t)jbase * QKV_LD + DMODEL     + h * HDIM;
            const float* vbaseg = qkv + (size_t)jbase * QKV_LD + 2*DMODEL   + h * HDIM;
            #pragma unroll
            for (int r = 0; r < 8; ++r) {
                const int j = lr + r * 8;
                kreg[r] = *(const float4*)&kbaseg[(size_t)j * QKV_LD + (lc << 2)];
                vreg[r] = *(const float4*)&vbaseg[(size_t)j * QKV_LD + (lc << 2)];
            }
        }
        __syncthreads();   // prior iteration done reading Kt/Vs/St
        {
            const int kb4 = lc << 2;
            #pragma unroll
            for (int r = 0; r < 8; ++r) {
                const int j = lr + r * 8;
                Kt[kb4+0][(swz(j >> 2, kb4+0) << 2) + (j & 3)] = kreg[r].x;
                Kt[kb4+1][(swz(j >> 2, kb4+1) << 2) + (j & 3)] = kreg[r].y;
                Kt[kb4+2][(swz(j >> 2, kb4+2) << 2) + (j & 3)] = kreg[r].z;
                Kt[kb4+3][(swz(j >> 2, kb4+3) << 2) + (j & 3)] = kreg[r].w;
                *(float4*)&Vs[j][kb4] = vreg[r];
            }
        }
        __syncthreads();

        // ---- S = scale * Q K^T, 4x4 per thread
        float s[4][4];
        #pragma unroll
        for (int i = 0; i < 4; ++i)
            #pragma unroll
            for (int j = 0; j < 4; ++j) s[i][j] = 0.f;

        #pragma unroll 8
        for (int k = 0; k < HDIM; ++k) {
            const float4 qv = *(const float4*)&Qt[k][swz(cq, k) << 2];
            const float4 kv = *(const float4*)&Kt[k][swz(cj, k) << 2];
            const float qa[4] = {qv.x, qv.y, qv.z, qv.w};
            const float ka[4] = {kv.x, kv.y, kv.z, kv.w};
            #pragma unroll
            for (int mm = 0; mm < 4; ++mm)
                #pragma unroll
                for (int jj = 0; jj < 4; ++jj)
                    s[mm][jj] = fmaf(qa[mm], ka[jj], s[mm][jj]);
        }

        const bool diag = (jt == qb);
        #pragma unroll
        for (int jj = 0; jj < 4; ++jj)
            #pragma unroll
            for (int mm = 0; mm < 4; ++mm) {
                float v = s[mm][jj] * scale;
                if (diag && (jbase + (cj << 2) + jj > row0 + (cq << 2) + mm))
                    v = -1.0e30f;   // masked
                St[(cj << 2) + jj][(cq << 2) + mm] = v;
            }
        __syncthreads();

        // ---- online softmax, parallel across all 256 threads
        // Phase A: per-segment max (each thread scans 16 of 64 j's for its row)
        {
            float tmax = -3.0e38f;
            #pragma unroll
            for (int i = 0; i < 16; ++i)
                tmax = fmaxf(tmax, St[(sseg << 4) + i][srow]);
            pmax[sseg][srow] = tmax;
        }
        __syncthreads();
        // Phase B: combine partials, update running max, publish corr
        if (t < QB) {
            float nm = fmaxf(fmaxf(pmax[0][t], pmax[1][t]),
                             fmaxf(pmax[2][t], pmax[3][t]));
            nm = fmaxf(m_run, nm);
            rowm[t]    = nm;
            rowstat[t] = __expf(m_run - nm);   // corr
            m_run = nm;
        }
        __syncthreads();
        // Phase C: exponentiate in place, per-segment sums
        {
            const float nm = rowm[srow];
            float rsum = 0.f;
            #pragma unroll
            for (int i = 0; i < 16; ++i) {
                const int j = (sseg << 4) + i;
                const float p = __expf(St[j][srow] - nm);
                St[j][srow] = p;
                rsum += p;
            }
            psum[sseg][srow] = rsum;
        }
        __syncthreads();
        // Phase D: fold into running denominator (register state in t<QB)
        if (t < QB) {
            l_run = l_run * rowstat[t]
                  + (psum[0][t] + psum[1][t] + psum[2][t] + psum[3][t]);
        }

        // ---- rescale O, accumulate P @ V
        {
            const float c0 = rowstat[om + 0];
            const float c1 = rowstat[om + 1];
            const float c2 = rowstat[om + 2];
            const float c3 = rowstat[om + 3];
            #pragma unroll
            for (int c = 0; c < 8; ++c) {
                o[0][c] *= c0; o[1][c] *= c1; o[2][c] *= c2; o[3][c] *= c3;
            }
            #pragma unroll 4
            for (int j = 0; j < KB; ++j) {
                const float4 p  = *(const float4*)&St[j][om];
                const float4 v0 = *(const float4*)&Vs[j][oc];
                const float4 v1 = *(const float4*)&Vs[j][oc + 64];
                const float pa[4] = {p.x, p.y, p.z, p.w};
                const float va[8] = {v0.x, v0.y, v0.z, v0.w, v1.x, v1.y, v1.z, v1.w};
                #pragma unroll
                for (int mm = 0; mm < 4; ++mm)
                    #pragma unroll
                    for (int c = 0; c < 8; ++c)
                        o[mm][c] = fmaf(pa[mm], va[c], o[mm][c]);
            }
        }
    }

    __syncthreads();
    if (t < QB) rowstat[t] = 1.f / l_run;
    __syncthreads();

    // ---- write out (row-major 2048x2048, this head's 128-col slice)
    float* obase = out + (size_t)row0 * DMODEL + h * HDIM;
    #pragma unroll
    for (int mm = 0; mm < 4; ++mm) {
        const float inv = rowstat[om + mm];
        const float4 r0 = make_float4(o[mm][0] * inv, o[mm][1] * inv, o[mm][2] * inv, o[mm][3] * inv);
        const float4 r1 = make_float4(o[mm][4] * inv, o[mm][5] * inv, o[mm][6] * inv, o[mm][7] * inv);
        *(float4*)&obase[(size_t)(om + mm) * DMODEL + oc]      = r0;
        *(float4*)&obase[(size_t)(om + mm) * DMODEL + 64 + oc] = r1;
    }
}

// ---------------------------------------------------------------------------
extern "C" void kernel_launch(void* const* d_in, const int* in_sizes, int n_in,
                              void* d_out, int out_size, void* d_ws, size_t ws_size,
                              hipStream_t stream)
{
    const float* x    = (const float*)d_in[0];
    const float* Wqkv = (const float*)d_in[1];
    const float* Wout = (const float*)d_in[2];
    float* outp = (float*)d_out;

    float* qkv  = (float*)d_ws;                          // 2048 x 6144 f32 (48 MB)
    float* attn = qkv + (size_t)N_SEQ * QKV_LD;          // 2048 x 2048 f32 (16 MB)

    // qkv = x @ W_qkv
    gemm_f32<<<dim3(QKV_LD / BN, N_SEQ / BM), 256, 0, stream>>>(
        x, Wqkv, qkv, N_SEQ, QKV_LD, DMODEL, DMODEL, QKV_LD, QKV_LD);

    // attn = causal_softmax(Q K^T / sqrt(dk)) V
    attn_f32<<<dim3(N_SEQ / QB, NHEAD), 256, 0, stream>>>(qkv, attn);

    // out = attn @ W_out
    gemm_f32<<<dim3(DMODEL / BN, N_SEQ / BM), 256, 0, stream>>>(
        attn, Wout, outp, N_SEQ, DMODEL, DMODEL, DMODEL, DMODEL, DMODEL);
}

// Round 3
// 474.214 us; speedup vs baseline: 3.3493x; 3.3493x over previous
//
#include <hip/hip_runtime.h>
#include <hip/hip_bf16.h>
#include <math.h>

#define N_SEQ  2048
#define DMODEL 2048
#define NHEAD  16
#define HDIM   128
#define QKV_LD 6144   // 3*DMODEL

typedef __attribute__((ext_vector_type(8))) short bf16x8;
typedef __attribute__((ext_vector_type(4))) float f32x4;

__device__ __forceinline__ ushort f2bf(float x) {
    union { float f; unsigned u; } v; v.f = x;
    unsigned r = (v.u + 0x7fffu + ((v.u >> 16) & 1u)) >> 16;
    return (ushort)r;
}
__device__ __forceinline__ float bf2f(ushort h) {
    union { unsigned u; float f; } v; v.u = ((unsigned)h) << 16;
    return v.f;
}

// ===========================================================================
// convert_split: fp32 [n] -> bf16 hi/lo same layout (vectorized float4)
// ===========================================================================
__global__ __launch_bounds__(256)
void convert_split(const float* __restrict__ in, ushort* __restrict__ oh,
                   ushort* __restrict__ ol, int n4)
{
    int i = blockIdx.x * 256 + threadIdx.x;
    if (i >= n4) return;
    float4 v = ((const float4*)in)[i];
    ushort4 h, l;
    h.x = f2bf(v.x); l.x = f2bf(v.x - bf2f(h.x));
    h.y = f2bf(v.y); l.y = f2bf(v.y - bf2f(h.y));
    h.z = f2bf(v.z); l.z = f2bf(v.z - bf2f(h.z));
    h.w = f2bf(v.w); l.w = f2bf(v.w - bf2f(h.w));
    ((ushort4*)oh)[i] = h;
    ((ushort4*)ol)[i] = l;
}

// ===========================================================================
// convert_split_t: fp32 [R][C] -> bf16 hi/lo transposed [C][R]
// ===========================================================================
__global__ __launch_bounds__(256)
void convert_split_t(const float* __restrict__ in, ushort* __restrict__ oh,
                     ushort* __restrict__ ol, int R, int C)
{
    __shared__ float T[64][65];
    const int t = threadIdx.x;
    const int c0 = blockIdx.x * 64, r0 = blockIdx.y * 64;
    #pragma unroll
    for (int p = 0; p < 4; ++p) {
        int r = (t >> 4) + p * 16;
        int c4 = (t & 15) * 4;
        float4 v = *(const float4*)&in[(size_t)(r0 + r) * C + c0 + c4];
        T[r][c4] = v.x; T[r][c4 + 1] = v.y; T[r][c4 + 2] = v.z; T[r][c4 + 3] = v.w;
    }
    __syncthreads();
    #pragma unroll
    for (int p = 0; p < 4; ++p) {
        int c = (t >> 4) + p * 16;
        int r4 = (t & 15) * 4;
        float f0 = T[r4][c], f1 = T[r4 + 1][c], f2 = T[r4 + 2][c], f3 = T[r4 + 3][c];
        ushort4 h, l;
        h.x = f2bf(f0); l.x = f2bf(f0 - bf2f(h.x));
        h.y = f2bf(f1); l.y = f2bf(f1 - bf2f(h.y));
        h.z = f2bf(f2); l.z = f2bf(f2 - bf2f(h.z));
        h.w = f2bf(f3); l.w = f2bf(f3 - bf2f(h.w));
        *(ushort4*)&oh[(size_t)(c0 + c) * R + r0 + r4] = h;
        *(ushort4*)&ol[(size_t)(c0 + c) * R + r0 + r4] = l;
    }
}

// ===========================================================================
// transpose_v: qkv_hi [2048][6144] cols 4096.. (= V bf16) -> vt [2048][2048]
// vt[(h*128+d)][n]
// ===========================================================================
__global__ __launch_bounds__(256)
void transpose_v(const ushort* __restrict__ qkvh, ushort* __restrict__ vt)
{
    __shared__ ushort T[64][72];
    const int t = threadIdx.x;
    const int c0 = blockIdx.x * 64, n0 = blockIdx.y * 64;
    #pragma unroll
    for (int p = 0; p < 2; ++p) {
        int r = (t >> 3) + p * 32;
        int u = (t & 7) * 8;
        *(bf16x8*)&T[r][u] = *(const bf16x8*)&qkvh[(size_t)(n0 + r) * QKV_LD + 2 * DMODEL + c0 + u];
    }
    __syncthreads();
    #pragma unroll
    for (int p = 0; p < 2; ++p) {
        int d = (t >> 3) + p * 32;
        int ju = (t & 7) * 8;
        bf16x8 o;
        #pragma unroll
        for (int i = 0; i < 8; ++i) o[i] = (short)T[ju + i][d];
        *(bf16x8*)&vt[(size_t)(c0 + d) * N_SEQ + n0 + ju] = o;
    }
}

// ===========================================================================
// bf16x3 GEMM: C[M][N] = (Ah+Al)[M][K] @ (Bh+Bl)^T  (B stored [N][K])
// 128x128 tile, BK=32, 256 thr (4 waves 2x2 of 64x64), mfma 16x16x32 bf16.
// C = Ah*Bh + Ah*Bl + Al*Bh (fp32 accum). LDS pitch 40 elems (80B) -> 2-way max.
// ===========================================================================
template<bool BF16OUT>
__global__ __launch_bounds__(256, 2)
void gemm_bf16x3(const ushort* __restrict__ Ah_g, const ushort* __restrict__ Al_g,
                 const ushort* __restrict__ Bh_g, const ushort* __restrict__ Bl_g,
                 ushort* __restrict__ Ch, ushort* __restrict__ Cl,
                 float* __restrict__ Cf, int M, int N, int K)
{
    __shared__ ushort Ah[128 * 40], Al[128 * 40], Bh[128 * 40], Bl[128 * 40];
    const int t = threadIdx.x;
    const int l = t & 63;
    const int w = t >> 6;
    const int l15 = l & 15, kgr = l >> 4;
    const int wm = (w >> 1) * 64, wn = (w & 1) * 64;
    const int bm = blockIdx.y * 128, bn = blockIdx.x * 128;
    const int sr = t >> 2, sku = (t & 3) * 8;

    f32x4 acc[4][4] = {};
    bf16x8 sA[4], sB[4];

    auto load_stage = [&](int k0) {
        const size_t a0 = (size_t)(bm + sr) * K + k0 + sku;
        const size_t a1 = (size_t)(bm + sr + 64) * K + k0 + sku;
        sA[0] = *(const bf16x8*)(Ah_g + a0);
        sA[1] = *(const bf16x8*)(Ah_g + a1);
        sA[2] = *(const bf16x8*)(Al_g + a0);
        sA[3] = *(const bf16x8*)(Al_g + a1);
        const size_t b0 = (size_t)(bn + sr) * K + k0 + sku;
        const size_t b1 = (size_t)(bn + sr + 64) * K + k0 + sku;
        sB[0] = *(const bf16x8*)(Bh_g + b0);
        sB[1] = *(const bf16x8*)(Bh_g + b1);
        sB[2] = *(const bf16x8*)(Bl_g + b0);
        sB[3] = *(const bf16x8*)(Bl_g + b1);
    };
    auto write_stage = [&]() {
        *(bf16x8*)&Ah[sr * 40 + sku]        = sA[0];
        *(bf16x8*)&Ah[(sr + 64) * 40 + sku] = sA[1];
        *(bf16x8*)&Al[sr * 40 + sku]        = sA[2];
        *(bf16x8*)&Al[(sr + 64) * 40 + sku] = sA[3];
        *(bf16x8*)&Bh[sr * 40 + sku]        = sB[0];
        *(bf16x8*)&Bh[(sr + 64) * 40 + sku] = sB[1];
        *(bf16x8*)&Bl[sr * 40 + sku]        = sB[2];
        *(bf16x8*)&Bl[(sr + 64) * 40 + sku] = sB[3];
    };

    load_stage(0);
    for (int k0 = 0; k0 < K; k0 += 32) {
        __syncthreads();
        write_stage();
        __syncthreads();
        if (k0 + 32 < K) load_stage(k0 + 32);

        bf16x8 ah[4], al[4], bh[4], bl[4];
        #pragma unroll
        for (int mf = 0; mf < 4; ++mf) {
            ah[mf] = *(const bf16x8*)&Ah[(wm + mf * 16 + l15) * 40 + kgr * 8];
            al[mf] = *(const bf16x8*)&Al[(wm + mf * 16 + l15) * 40 + kgr * 8];
        }
        #pragma unroll
        for (int nf = 0; nf < 4; ++nf) {
            bh[nf] = *(const bf16x8*)&Bh[(wn + nf * 16 + l15) * 40 + kgr * 8];
            bl[nf] = *(const bf16x8*)&Bl[(wn + nf * 16 + l15) * 40 + kgr * 8];
        }
        #pragma unroll
        for (int mf = 0; mf < 4; ++mf)
            #pragma unroll
            for (int nf = 0; nf < 4; ++nf) {
                acc[mf][nf] = __builtin_amdgcn_mfma_f32_16x16x32_bf16(ah[mf], bh[nf], acc[mf][nf], 0, 0, 0);
                acc[mf][nf] = __builtin_amdgcn_mfma_f32_16x16x32_bf16(ah[mf], bl[nf], acc[mf][nf], 0, 0, 0);
                acc[mf][nf] = __builtin_amdgcn_mfma_f32_16x16x32_bf16(al[mf], bh[nf], acc[mf][nf], 0, 0, 0);
            }
    }

    #pragma unroll
    for (int mf = 0; mf < 4; ++mf)
        #pragma unroll
        for (int nf = 0; nf < 4; ++nf)
            #pragma unroll
            for (int r = 0; r < 4; ++r) {
                const int m = bm + wm + mf * 16 + kgr * 4 + r;
                const int n = bn + wn + nf * 16 + l15;
                const float v = acc[mf][nf][r];
                if constexpr (BF16OUT) {
                    ushort h = f2bf(v);
                    Ch[(size_t)m * N + n] = h;
                    Cl[(size_t)m * N + n] = f2bf(v - bf2f(h));
                } else {
                    Cf[(size_t)m * N + n] = v;
                }
            }
}

// ===========================================================================
// MFMA flash attention. grid (32 qtiles, 16 heads), 256 thr (4 waves).
// Wave w: q rows [qb*64+w*16, +16). Q hi/lo in regs; K hi/lo + V^T in LDS.
// QK^T = Qh*Kh + Qh*Kl + Ql*Kh; softmax in-register (16-lane butterfly);
// P bf16 -> per-wave LDS; PV plain bf16 MFMA.
// ===========================================================================
__global__ __launch_bounds__(256, 2)
void attn_mfma(const ushort* __restrict__ qkvh, const ushort* __restrict__ qkvl,
               const ushort* __restrict__ vt,
               ushort* __restrict__ oh, ushort* __restrict__ ol)
{
    __shared__ ushort Kh[64 * 136], Kl[64 * 136], Vts[128 * 72], St[4 * 16 * 72];
    const int t = threadIdx.x;
    const int l = t & 63;
    const int w = t >> 6;
    const int l15 = l & 15, kgr = l >> 4;
    const int h = blockIdx.y, qb = blockIdx.x;
    const int q0 = qb * 64 + w * 16;

    // Q fragments in registers (hi/lo), rows q0+l15, k = kc*32 + kgr*8
    bf16x8 qh[4], ql[4];
    {
        const size_t base = (size_t)(q0 + l15) * QKV_LD + h * HDIM;
        #pragma unroll
        for (int kc = 0; kc < 4; ++kc) {
            qh[kc] = *(const bf16x8*)(qkvh + base + kc * 32 + kgr * 8);
            ql[kc] = *(const bf16x8*)(qkvl + base + kc * 32 + kgr * 8);
        }
    }

    f32x4 o[8] = {};
    float m_run[4], l_run[4];
    #pragma unroll
    for (int r = 0; r < 4; ++r) { m_run[r] = -1e30f; l_run[r] = 0.f; }

    bf16x8 sKh[4], sKl[4], sV[4];
    auto load_tile = [&](int jb) {
        #pragma unroll
        for (int i = 0; i < 4; ++i) {
            int r = (t >> 4) + i * 16;
            size_t g = (size_t)(jb + r) * QKV_LD + DMODEL + h * HDIM + (t & 15) * 8;
            sKh[i] = *(const bf16x8*)(qkvh + g);
            sKl[i] = *(const bf16x8*)(qkvl + g);
        }
        #pragma unroll
        for (int i = 0; i < 4; ++i) {
            int d = (t >> 3) + i * 32;
            sV[i] = *(const bf16x8*)(vt + (size_t)(h * HDIM + d) * N_SEQ + jb + (t & 7) * 8);
        }
    };
    auto write_tile = [&]() {
        #pragma unroll
        for (int i = 0; i < 4; ++i) {
            int r = (t >> 4) + i * 16;
            *(bf16x8*)&Kh[r * 136 + (t & 15) * 8] = sKh[i];
            *(bf16x8*)&Kl[r * 136 + (t & 15) * 8] = sKl[i];
        }
        #pragma unroll
        for (int i = 0; i < 4; ++i) {
            int d = (t >> 3) + i * 32;
            *(bf16x8*)&Vts[d * 72 + (t & 7) * 8] = sV[i];
        }
    };

    const float scale = 0.08838834764831845f;  // 1/sqrt(128)

    load_tile(0);
    for (int jt = 0; jt <= qb; ++jt) {
        const int jb = jt * 64;
        __syncthreads();
        write_tile();
        __syncthreads();
        if (jt < qb) load_tile(jb + 64);

        // ---- S = scale * Q K^T (+causal mask; exact for non-diag tiles too)
        float sv[4][4];
        #pragma unroll
        for (int jf = 0; jf < 4; ++jf) {
            f32x4 sacc = {};
            #pragma unroll
            for (int kc = 0; kc < 4; ++kc) {
                bf16x8 kh = *(const bf16x8*)&Kh[(jf * 16 + l15) * 136 + kc * 32 + kgr * 8];
                bf16x8 kl = *(const bf16x8*)&Kl[(jf * 16 + l15) * 136 + kc * 32 + kgr * 8];
                sacc = __builtin_amdgcn_mfma_f32_16x16x32_bf16(qh[kc], kh, sacc, 0, 0, 0);
                sacc = __builtin_amdgcn_mfma_f32_16x16x32_bf16(qh[kc], kl, sacc, 0, 0, 0);
                sacc = __builtin_amdgcn_mfma_f32_16x16x32_bf16(ql[kc], kh, sacc, 0, 0, 0);
            }
            const int j = jb + jf * 16 + l15;
            #pragma unroll
            for (int r = 0; r < 4; ++r) {
                const int q = q0 + kgr * 4 + r;
                sv[jf][r] = (j > q) ? -1e30f : sacc[r] * scale;
            }
        }

        // ---- online softmax, fully in-register (reduce over 16 j-lanes)
        float corr[4], p[4][4];
        #pragma unroll
        for (int r = 0; r < 4; ++r) {
            float tm = fmaxf(fmaxf(sv[0][r], sv[1][r]), fmaxf(sv[2][r], sv[3][r]));
            tm = fmaxf(tm, __shfl_xor(tm, 1));
            tm = fmaxf(tm, __shfl_xor(tm, 2));
            tm = fmaxf(tm, __shfl_xor(tm, 4));
            tm = fmaxf(tm, __shfl_xor(tm, 8));
            const float nm = fmaxf(m_run[r], tm);
            corr[r] = __expf(m_run[r] - nm);
            m_run[r] = nm;
            float rs = 0.f;
            #pragma unroll
            for (int jf = 0; jf < 4; ++jf) { p[jf][r] = __expf(sv[jf][r] - nm); rs += p[jf][r]; }
            rs += __shfl_xor(rs, 1);
            rs += __shfl_xor(rs, 2);
            rs += __shfl_xor(rs, 4);
            rs += __shfl_xor(rs, 8);
            l_run[r] = l_run[r] * corr[r] + rs;
        }

        // ---- P -> per-wave LDS (bf16), then rescale O and accumulate P@V
        #pragma unroll
        for (int jf = 0; jf < 4; ++jf)
            #pragma unroll
            for (int r = 0; r < 4; ++r)
                St[w * 1152 + (kgr * 4 + r) * 72 + jf * 16 + l15] = f2bf(p[jf][r]);

        #pragma unroll
        for (int df = 0; df < 8; ++df)
            #pragma unroll
            for (int r = 0; r < 4; ++r) o[df][r] *= corr[r];

        #pragma unroll
        for (int jc = 0; jc < 2; ++jc) {
            bf16x8 pa = *(const bf16x8*)&St[w * 1152 + l15 * 72 + jc * 32 + kgr * 8];
            #pragma unroll
            for (int df = 0; df < 8; ++df) {
                bf16x8 vb = *(const bf16x8*)&Vts[(df * 16 + l15) * 72 + jc * 32 + kgr * 8];
                o[df] = __builtin_amdgcn_mfma_f32_16x16x32_bf16(pa, vb, o[df], 0, 0, 0);
            }
        }
    }

    // ---- epilogue: O /= l, write attn hi/lo
    #pragma unroll
    for (int r = 0; r < 4; ++r) l_run[r] = 1.f / l_run[r];
    #pragma unroll
    for (int df = 0; df < 8; ++df)
        #pragma unroll
        for (int r = 0; r < 4; ++r) {
            const float v = o[df][r] * l_run[r];
            const size_t a = (size_t)(q0 + kgr * 4 + r) * DMODEL + h * HDIM + df * 16 + l15;
            const ushort hh = f2bf(v);
            oh[a] = hh;
            ol[a] = f2bf(v - bf2f(hh));
        }
}

// ===========================================================================
// fp32 fallback path (round-2 verified kernels) — used if ws_size too small
// ===========================================================================
#define BM 128
#define BN 128
#define BKG 16

__global__ __launch_bounds__(256, 2)
void gemm_f32(const float* __restrict__ A, const float* __restrict__ B,
              float* __restrict__ C, int M, int N, int K,
              int lda, int ldb, int ldc)
{
    __shared__ float As[BKG][132];
    __shared__ float Bs[BKG][132];
    const int t = threadIdx.x;
    const int tx = t & 15, ty = t >> 4;
    const int bm = blockIdx.y * BM, bn = blockIdx.x * BN;
    const int am = t >> 2, ak = (t & 3) << 2;
    const int bk = t >> 5, bn4 = (t & 31) << 2;
    float acc[8][8];
    #pragma unroll
    for (int i = 0; i < 8; ++i)
        #pragma unroll
        for (int j = 0; j < 8; ++j) acc[i][j] = 0.f;
    for (int k0 = 0; k0 < K; k0 += BKG) {
        const float4 a0 = *(const float4*)&A[(size_t)(bm + am) * lda + k0 + ak];
        const float4 a1 = *(const float4*)&A[(size_t)(bm + am + 64) * lda + k0 + ak];
        const float4 b0 = *(const float4*)&B[(size_t)(k0 + bk) * ldb + bn + bn4];
        const float4 b1 = *(const float4*)&B[(size_t)(k0 + bk + 8) * ldb + bn + bn4];
        __syncthreads();
        As[ak + 0][am] = a0.x; As[ak + 1][am] = a0.y; As[ak + 2][am] = a0.z; As[ak + 3][am] = a0.w;
        As[ak + 0][am + 64] = a1.x; As[ak + 1][am + 64] = a1.y; As[ak + 2][am + 64] = a1.z; As[ak + 3][am + 64] = a1.w;
        *(float4*)&Bs[bk][bn4] = b0;
        *(float4*)&Bs[bk + 8][bn4] = b1;
        __syncthreads();
        #pragma unroll
        for (int kk = 0; kk < BKG; ++kk) {
            const float4 A0 = *(const float4*)&As[kk][ty << 2];
            const float4 A1 = *(const float4*)&As[kk][(ty << 2) + 64];
            const float4 B0 = *(const float4*)&Bs[kk][tx << 2];
            const float4 B1 = *(const float4*)&Bs[kk][(tx << 2) + 64];
            const float a[8] = {A0.x, A0.y, A0.z, A0.w, A1.x, A1.y, A1.z, A1.w};
            const float b[8] = {B0.x, B0.y, B0.z, B0.w, B1.x, B1.y, B1.z, B1.w};
            #pragma unroll
            for (int i = 0; i < 8; ++i)
                #pragma unroll
                for (int j = 0; j < 8; ++j) acc[i][j] = fmaf(a[i], b[j], acc[i][j]);
        }
    }
    #pragma unroll
    for (int i = 0; i < 8; ++i) {
        const int m = bm + ((i < 4) ? ((ty << 2) + i) : (64 + (ty << 2) + i - 4));
        const float4 o0 = make_float4(acc[i][0], acc[i][1], acc[i][2], acc[i][3]);
        const float4 o1 = make_float4(acc[i][4], acc[i][5], acc[i][6], acc[i][7]);
        *(float4*)&C[(size_t)m * ldc + bn + (tx << 2)] = o0;
        *(float4*)&C[(size_t)m * ldc + bn + 64 + (tx << 2)] = o1;
    }
}

#define QB 64
#define KB 64
#define PQT 68

__device__ __forceinline__ int swz(int c, int k) { return c ^ ((k >> 3) & 7); }

__global__ __launch_bounds__(256, 1)
void attn_f32(const float* __restrict__ qkv, float* __restrict__ out)
{
    __shared__ float Qt[HDIM][PQT];
    __shared__ float Kt[HDIM][PQT];
    __shared__ float Vs[KB][132];
    __shared__ float Sf[KB][PQT];
    __shared__ float pmax[4][QB];
    __shared__ float psum[4][QB];
    __shared__ float rowm[QB];
    __shared__ float rowstat[QB];
    const int t = threadIdx.x;
    const int h = blockIdx.y, qb = blockIdx.x;
    const int row0 = qb * QB;
    const int lc = t & 31, lr = t >> 5;
    {
        const float* qbase = qkv + (size_t)row0 * QKV_LD + h * HDIM;
        #pragma unroll
        for (int r = 0; r < 8; ++r) {
            const int m = lr + r * 8;
            const float4 q = *(const float4*)&qbase[(size_t)m * QKV_LD + (lc << 2)];
            const int kb4 = lc << 2;
            Qt[kb4 + 0][(swz(m >> 2, kb4 + 0) << 2) + (m & 3)] = q.x;
            Qt[kb4 + 1][(swz(m >> 2, kb4 + 1) << 2) + (m & 3)] = q.y;
            Qt[kb4 + 2][(swz(m >> 2, kb4 + 2) << 2) + (m & 3)] = q.z;
            Qt[kb4 + 3][(swz(m >> 2, kb4 + 3) << 2) + (m & 3)] = q.w;
        }
    }
    float m_run = -3.0e38f, l_run = 0.f;
    float o[4][8];
    #pragma unroll
    for (int i = 0; i < 4; ++i)
        #pragma unroll
        for (int j = 0; j < 8; ++j) o[i][j] = 0.f;
    const int cq = t & 15, cj = t >> 4;
    const int om = (t >> 4) << 2, oc = (t & 15) << 2;
    const int srow = t & 63, sseg = t >> 6;
    const float scale = 0.08838834764831845f;
    const int ntiles = qb + 1;
    for (int jt = 0; jt < ntiles; ++jt) {
        const int jbase = jt * KB;
        float4 kreg[8], vreg[8];
        {
            const float* kbaseg = qkv + (size_t)jbase * QKV_LD + DMODEL + h * HDIM;
            const float* vbaseg = qkv + (size_t)jbase * QKV_LD + 2 * DMODEL + h * HDIM;
            #pragma unroll
            for (int r = 0; r < 8; ++r) {
                const int j = lr + r * 8;
                kreg[r] = *(const float4*)&kbaseg[(size_t)j * QKV_LD + (lc << 2)];
                vreg[r] = *(const float4*)&vbaseg[(size_t)j * QKV_LD + (lc << 2)];
            }
        }
        __syncthreads();
        {
            const int kb4 = lc << 2;
            #pragma unroll
            for (int r = 0; r < 8; ++r) {
                const int j = lr + r * 8;
                Kt[kb4 + 0][(swz(j >> 2, kb4 + 0) << 2) + (j & 3)] = kreg[r].x;
                Kt[kb4 + 1][(swz(j >> 2, kb4 + 1) << 2) + (j & 3)] = kreg[r].y;
                Kt[kb4 + 2][(swz(j >> 2, kb4 + 2) << 2) + (j & 3)] = kreg[r].z;
                Kt[kb4 + 3][(swz(j >> 2, kb4 + 3) << 2) + (j & 3)] = kreg[r].w;
                *(float4*)&Vs[j][kb4] = vreg[r];
            }
        }
        __syncthreads();
        float s[4][4];
        #pragma unroll
        for (int i = 0; i < 4; ++i)
            #pragma unroll
            for (int j = 0; j < 4; ++j) s[i][j] = 0.f;
        #pragma unroll 8
        for (int k = 0; k < HDIM; ++k) {
            const float4 qv = *(const float4*)&Qt[k][swz(cq, k) << 2];
            const float4 kv = *(const float4*)&Kt[k][swz(cj, k) << 2];
            const float qa[4] = {qv.x, qv.y, qv.z, qv.w};
            const float ka[4] = {kv.x, kv.y, kv.z, kv.w};
            #pragma unroll
            for (int mm = 0; mm < 4; ++mm)
                #pragma unroll
                for (int jj = 0; jj < 4; ++jj) s[mm][jj] = fmaf(qa[mm], ka[jj], s[mm][jj]);
        }
        const bool diag = (jt == qb);
        #pragma unroll
        for (int jj = 0; jj < 4; ++jj)
            #pragma unroll
            for (int mm = 0; mm < 4; ++mm) {
                float v = s[mm][jj] * scale;
                if (diag && (jbase + (cj << 2) + jj > row0 + (cq << 2) + mm)) v = -1.0e30f;
                Sf[(cj << 2) + jj][(cq << 2) + mm] = v;
            }
        __syncthreads();
        {
            float tmax = -3.0e38f;
            #pragma unroll
            for (int i = 0; i < 16; ++i) tmax = fmaxf(tmax, Sf[(sseg << 4) + i][srow]);
            pmax[sseg][srow] = tmax;
        }
        __syncthreads();
        if (t < QB) {
            float nm = fmaxf(fmaxf(pmax[0][t], pmax[1][t]), fmaxf(pmax[2][t], pmax[3][t]));
            nm = fmaxf(m_run, nm);
            rowm[t] = nm;
            rowstat[t] = __expf(m_run - nm);
            m_run = nm;
        }
        __syncthreads();
        {
            const float nm = rowm[srow];
            float rsum = 0.f;
            #pragma unroll
            for (int i = 0; i < 16; ++i) {
                const int j = (sseg << 4) + i;
                const float p = __expf(Sf[j][srow] - nm);
                Sf[j][srow] = p;
                rsum += p;
            }
            psum[sseg][srow] = rsum;
        }
        __syncthreads();
        if (t < QB) {
            l_run = l_run * rowstat[t] + (psum[0][t] + psum[1][t] + psum[2][t] + psum[3][t]);
        }
        {
            const float c0 = rowstat[om + 0], c1 = rowstat[om + 1];
            const float c2 = rowstat[om + 2], c3 = rowstat[om + 3];
            #pragma unroll
            for (int c = 0; c < 8; ++c) { o[0][c] *= c0; o[1][c] *= c1; o[2][c] *= c2; o[3][c] *= c3; }
            #pragma unroll 4
            for (int j = 0; j < KB; ++j) {
                const float4 p = *(const float4*)&Sf[j][om];
                const float4 v0 = *(const float4*)&Vs[j][oc];
                const float4 v1 = *(const float4*)&Vs[j][oc + 64];
                const float pa[4] = {p.x, p.y, p.z, p.w};
                const float va[8] = {v0.x, v0.y, v0.z, v0.w, v1.x, v1.y, v1.z, v1.w};
                #pragma unroll
                for (int mm = 0; mm < 4; ++mm)
                    #pragma unroll
                    for (int c = 0; c < 8; ++c) o[mm][c] = fmaf(pa[mm], va[c], o[mm][c]);
            }
        }
    }
    __syncthreads();
    if (t < QB) rowstat[t] = 1.f / l_run;
    __syncthreads();
    float* obase = out + (size_t)row0 * DMODEL + h * HDIM;
    #pragma unroll
    for (int mm = 0; mm < 4; ++mm) {
        const float inv = rowstat[om + mm];
        const float4 r0 = make_float4(o[mm][0] * inv, o[mm][1] * inv, o[mm][2] * inv, o[mm][3] * inv);
        const float4 r1 = make_float4(o[mm][4] * inv, o[mm][5] * inv, o[mm][6] * inv, o[mm][7] * inv);
        *(float4*)&obase[(size_t)(om + mm) * DMODEL + oc] = r0;
        *(float4*)&obase[(size_t)(om + mm) * DMODEL + 64 + oc] = r1;
    }
}

// ===========================================================================
extern "C" void kernel_launch(void* const* d_in, const int* in_sizes, int n_in,
                              void* d_out, int out_size, void* d_ws, size_t ws_size,
                              hipStream_t stream)
{
    const float* x    = (const float*)d_in[0];
    const float* Wqkv = (const float*)d_in[1];
    const float* Wout = (const float*)d_in[2];
    float* outp = (float*)d_out;

    // ws layout (bytes):
    //  [0, 8M)       x_hi   -> later attn_hi
    //  [8M, 16M)     x_lo   -> later attn_lo
    //  [16M, 64M)    wqkvt hi/lo -> later woutt hi/lo + vt
    //  [64M, 112M)   qkv hi/lo
    const size_t O_XHI = 0;
    const size_t O_XLO = 8388608;
    const size_t O_WT  = 16777216;
    const size_t O_QKV = 67108864;
    const size_t NEED  = 117440512;

    char* ws = (char*)d_ws;
    if (ws_size >= NEED) {
        ushort* x_hi   = (ushort*)(ws + O_XHI);
        ushort* x_lo   = (ushort*)(ws + O_XLO);
        ushort* wqt_hi = (ushort*)(ws + O_WT);
        ushort* wqt_lo = (ushort*)(ws + O_WT + 25165824);
        ushort* qkv_hi = (ushort*)(ws + O_QKV);
        ushort* qkv_lo = (ushort*)(ws + O_QKV + 25165824);
        // after GEMM1 these alias the (dead) wqkvt region:
        ushort* wot_hi = (ushort*)(ws + O_WT);
        ushort* wot_lo = (ushort*)(ws + O_WT + 8388608);
        ushort* vt     = (ushort*)(ws + O_WT + 16777216);
        // after GEMM1 these alias the (dead) x region:
        ushort* at_hi  = (ushort*)(ws + O_XHI);
        ushort* at_lo  = (ushort*)(ws + O_XLO);

        // 1. split x
        convert_split<<<dim3(N_SEQ * DMODEL / 4 / 256), 256, 0, stream>>>(
            x, x_hi, x_lo, N_SEQ * DMODEL / 4);
        // 2. split + transpose Wqkv -> [6144][2048]
        convert_split_t<<<dim3(QKV_LD / 64, DMODEL / 64), 256, 0, stream>>>(
            Wqkv, wqt_hi, wqt_lo, DMODEL, QKV_LD);
        // 3. qkv = x @ Wqkv  (bf16 hi/lo out)
        gemm_bf16x3<true><<<dim3(QKV_LD / 128, N_SEQ / 128), 256, 0, stream>>>(
            x_hi, x_lo, wqt_hi, wqt_lo, qkv_hi, qkv_lo, nullptr,
            N_SEQ, QKV_LD, DMODEL);
        // 4. split + transpose Wout -> [2048][2048]  (into dead wqkvt region)
        convert_split_t<<<dim3(DMODEL / 64, DMODEL / 64), 256, 0, stream>>>(
            Wout, wot_hi, wot_lo, DMODEL, DMODEL);
        // 5. transpose V (bf16 hi only)
        transpose_v<<<dim3(DMODEL / 64, N_SEQ / 64), 256, 0, stream>>>(qkv_hi, vt);
        // 6. attention (writes attn hi/lo into dead x region)
        attn_mfma<<<dim3(N_SEQ / 64, NHEAD), 256, 0, stream>>>(
            qkv_hi, qkv_lo, vt, at_hi, at_lo);
        // 7. out = attn @ Wout (fp32 out)
        gemm_bf16x3<false><<<dim3(DMODEL / 128, N_SEQ / 128), 256, 0, stream>>>(
            at_hi, at_lo, wot_hi, wot_lo, nullptr, nullptr, outp,
            N_SEQ, DMODEL, DMODEL);
    } else {
        // fp32 fallback (round-2 verified path)
        float* qkv  = (float*)d_ws;
        float* attn = qkv + (size_t)N_SEQ * QKV_LD;
        gemm_f32<<<dim3(QKV_LD / BN, N_SEQ / BM), 256, 0, stream>>>(
            x, Wqkv, qkv, N_SEQ, QKV_LD, DMODEL, DMODEL, QKV_LD, QKV_LD);
        attn_f32<<<dim3(N_SEQ / QB, NHEAD), 256, 0, stream>>>(qkv, attn);
        gemm_f32<<<dim3(DMODEL / BN, N_SEQ / BM), 256, 0, stream>>>(
            attn, Wout, outp, N_SEQ, DMODEL, DMODEL, DMODEL, DMODEL, DMODEL);
    }
}